// Round 3
// baseline (544.993 us; speedup 1.0000x reference)
//
#include <hip/hip_runtime.h>
#include <hip/hip_bf16.h>

#define BB 8
#define SS 4096
#define DD 128
#define HH 8
#define NBUCK 64
#define CHUNKSZ 64
#define NCHUNK 512      // HH*SS/CHUNKSZ
#define HSTOT 32768     // HH*SS
#define PK 132          // padded LDS row stride (floats)

static __device__ __forceinline__ unsigned short f2bf_rne(float f) {
    unsigned int x = __float_as_uint(f);
    unsigned int r = (x + 0x7fffu + ((x >> 16) & 1u)) >> 16;
    return (unsigned short)r;
}
static __device__ __forceinline__ float bf2f(unsigned short u) {
    return __uint_as_float(((unsigned int)u) << 16);
}

// ---------------- Kernel A: LSH hashing (f64 accumulate for argmax safety) ----
__global__ __launch_bounds__(256) void hash_kernel(
    const float* __restrict__ qk, const float* __restrict__ rot,
    unsigned char* __restrict__ bucket_ws, float* __restrict__ bucket_out)
{
    __shared__ float qtile[32 * PK];
    const int tid = threadIdx.x;
    const int blk = blockIdx.x;            // 0..1023 = b*128 + tblk
    const int b  = blk >> 7;
    const int t0 = (blk & 127) * 32;

    const float* src = qk + ((size_t)b * SS + t0) * DD;
    #pragma unroll
    for (int c = 0; c < 4; ++c) {
        int idx = c * 1024 + tid * 4;
        float4 val = *reinterpret_cast<const float4*>(src + idx);
        int row = idx >> 7, col = idx & 127;
        *reinterpret_cast<float4*>(&qtile[row * PK + col]) = val;
    }
    __syncthreads();

    const int i = tid & 31;   // token within tile
    const int h = tid >> 5;   // hash round
    double acc[32];
    #pragma unroll
    for (int j = 0; j < 32; ++j) acc[j] = 0.0;

    const float* rbase = rot + h * 32;     // rotations[f][h][j]: f stride 256
    for (int f = 0; f < DD; ++f) {
        double qd = (double)qtile[i * PK + f];
        const float4* r4 = reinterpret_cast<const float4*>(rbase + (size_t)f * (HH * 32));
        #pragma unroll
        for (int j4 = 0; j4 < 8; ++j4) {
            float4 rv = r4[j4];
            acc[j4*4+0] = fma(qd, (double)rv.x, acc[j4*4+0]);
            acc[j4*4+1] = fma(qd, (double)rv.y, acc[j4*4+1]);
            acc[j4*4+2] = fma(qd, (double)rv.z, acc[j4*4+2]);
            acc[j4*4+3] = fma(qd, (double)rv.w, acc[j4*4+3]);
        }
    }

    // argmax over [rot, -rot], first-occurrence tie semantics
    float bv = -3.0e38f; int bi = 0;
    #pragma unroll
    for (int j = 0; j < 32; ++j) { float r = (float)acc[j];  if (r > bv) { bv = r; bi = j; } }
    #pragma unroll
    for (int j = 0; j < 32; ++j) { float r = -(float)acc[j]; if (r > bv) { bv = r; bi = 32 + j; } }

    size_t o = ((size_t)b * HH + h) * SS + (t0 + i);
    bucket_ws[o]  = (unsigned char)bi;
    bucket_out[o] = (float)(bi + h * NBUCK);
}

// ---------------- Kernel B: stable counting sort per (b,h) -------------------
__global__ __launch_bounds__(256) void sort_kernel(
    const unsigned char* __restrict__ bucket_ws, int* __restrict__ st)
{
    __shared__ unsigned int hist[256 * 65];   // padded stride 65
    __shared__ unsigned int totals[64];
    const int tid = threadIdx.x;
    const int bh  = blockIdx.x;               // 0..63 = b*8+h

    unsigned int* hrow = &hist[tid * 65];
    #pragma unroll
    for (int j = 0; j < 65; ++j) hrow[j] = 0u;

    const uint4 raw = *reinterpret_cast<const uint4*>(bucket_ws + (size_t)bh * SS + tid * 16);
    unsigned int w[4] = {raw.x, raw.y, raw.z, raw.w};

    #pragma unroll
    for (int c = 0; c < 16; ++c) {
        unsigned int bk = (w[c >> 2] >> ((c & 3) * 8)) & 255u;
        hrow[bk] += 1u;
    }
    __syncthreads();

    if (tid < 64) {                            // per-bucket exclusive scan over chunks
        unsigned int run = 0;
        for (int c2 = 0; c2 < 256; ++c2) {
            unsigned int x = hist[c2 * 65 + tid];
            hist[c2 * 65 + tid] = run;
            run += x;
        }
        totals[tid] = run;
    }
    __syncthreads();
    if (tid == 0) {                            // exclusive scan over buckets
        unsigned int base = 0;
        for (int k = 0; k < 64; ++k) { unsigned int x = totals[k]; totals[k] = base; base += x; }
    }
    __syncthreads();

    int* dst = st + (size_t)bh * SS;
    #pragma unroll
    for (int c = 0; c < 16; ++c) {
        unsigned int bk = (w[c >> 2] >> ((c & 3) * 8)) & 255u;
        unsigned int pos = totals[bk] + hrow[bk];
        hrow[bk] += 1u;
        dst[pos] = tid * 16 + c;               // token id, stable by t
    }
}

// ---------------- Kernel C: chunked attention --------------------------------
__global__ __launch_bounds__(256) void attn_kernel(
    const float* __restrict__ qk, const float* __restrict__ vv,
    const int* __restrict__ st, float* __restrict__ logits_ws,
    void* __restrict__ o_ws, const int obf16)
{
    __shared__ float smem[64 * PK + 128 * PK + 512];
    float* Qs    = smem;                               // 8448 floats; reused as probs
    float* Ks    = smem + 64 * PK;                     // 16896 floats; reused as V
    int*   tks   = (int*)(smem + 64 * PK + 128 * PK);  // 128 token ids
    float* ninvs = smem + 64 * PK + 128 * PK + 128;    // 128
    float* psums = smem + 64 * PK + 128 * PK + 256;    // 256

    const int tid = threadIdx.x;
    const int bc  = blockIdx.x;
    const int b   = bc >> 9;
    const int c   = bc & 511;
    const int h   = c >> 6;

    if (tid < 128) {
        int src_c = (tid < 64) ? c : ((c == 0) ? (NCHUNK - 1) : (c - 1));
        tks[tid] = st[(size_t)b * HSTOT + (size_t)src_c * CHUNKSZ + (tid & 63)];
    }
    __syncthreads();

    // K rows (gather) + per-half sum-of-squares
    {
        const int k = tid >> 1, half = tid & 1;
        const int t = tks[k];
        const float4* srow = reinterpret_cast<const float4*>(qk + ((size_t)b * SS + t) * DD + half * 64);
        float4* drow = reinterpret_cast<float4*>(Ks + k * PK + half * 64);
        float ss = 0.f;
        #pragma unroll
        for (int c4 = 0; c4 < 16; ++c4) {
            float4 val = srow[c4];
            drow[c4] = val;
            ss = fmaf(val.x, val.x, ss); ss = fmaf(val.y, val.y, ss);
            ss = fmaf(val.z, val.z, ss); ss = fmaf(val.w, val.w, ss);
        }
        psums[tid] = ss;
    }
    // Q rows (gather)
    {
        const int q = tid >> 2, quarter = tid & 3;
        const int t = tks[q];
        const float4* srow = reinterpret_cast<const float4*>(qk + ((size_t)b * SS + t) * DD + quarter * 32);
        float4* drow = reinterpret_cast<float4*>(Qs + q * PK + quarter * 32);
        #pragma unroll
        for (int c4 = 0; c4 < 8; ++c4) drow[c4] = srow[c4];
    }
    __syncthreads();
    if (tid < 128) ninvs[tid] = rsqrtf(psums[2 * tid] + psums[2 * tid + 1] + 1e-6f);
    __syncthreads();

    // dots: thread (ty,tx): queries ty+16a, keys tx+16e
    const int ty = tid >> 4;
    const int tx = tid & 15;

    float acc[4][8];
    #pragma unroll
    for (int a = 0; a < 4; ++a)
        #pragma unroll
        for (int e = 0; e < 8; ++e) acc[a][e] = 0.f;

    for (int d = 0; d < DD; d += 4) {
        float4 qv[4], kv[8];
        #pragma unroll
        for (int a = 0; a < 4; ++a)
            qv[a] = *reinterpret_cast<const float4*>(&Qs[(ty + 16 * a) * PK + d]);
        #pragma unroll
        for (int e = 0; e < 8; ++e)
            kv[e] = *reinterpret_cast<const float4*>(&Ks[(tx + 16 * e) * PK + d]);
        #pragma unroll
        for (int a = 0; a < 4; ++a)
            #pragma unroll
            for (int e = 0; e < 8; ++e) {
                float s = acc[a][e];
                s = fmaf(qv[a].x, kv[e].x, s);
                s = fmaf(qv[a].y, kv[e].y, s);
                s = fmaf(qv[a].z, kv[e].z, s);
                s = fmaf(qv[a].w, kv[e].w, s);
                acc[a][e] = s;
            }
    }
    __syncthreads();   // everyone done reading Qs/Ks

    // scale, self-mask, row softmax (reduce across 16 tx lanes), probs -> Qs
    const float SCALE = 0.088388347648318447f;   // 128^-0.5
    #pragma unroll
    for (int a = 0; a < 4; ++a) {
        const int q  = ty + 16 * a;
        const int tq = tks[q];
        float pr[8];
        float m = -3.0e38f;
        #pragma unroll
        for (int e = 0; e < 8; ++e) {
            const int k = tx + 16 * e;
            float val = acc[a][e] * ninvs[k] * SCALE;
            if (tks[k] == tq) val = -1e5f;
            pr[e] = val;
            m = fmaxf(m, val);
        }
        #pragma unroll
        for (int off = 1; off < 16; off <<= 1) m = fmaxf(m, __shfl_xor(m, off));
        float ssum = 0.f;
        #pragma unroll
        for (int e = 0; e < 8; ++e) { float ex = expf(pr[e] - m); pr[e] = ex; ssum += ex; }
        #pragma unroll
        for (int off = 1; off < 16; off <<= 1) ssum += __shfl_xor(ssum, off);
        const float inv = 1.0f / ssum;
        #pragma unroll
        for (int e = 0; e < 8; ++e)
            Qs[q * PK + tx + 16 * e] = pr[e] * inv;
        if (tx == 0)
            logits_ws[((size_t)b * HH + h) * SS + tq] = m + logf(ssum);
    }
    __syncthreads();   // probs written; Ks free for V

    // V rows (gather) into Ks region
    {
        const int k = tid >> 1, half = tid & 1;
        const int t = tks[k];
        const float4* srow = reinterpret_cast<const float4*>(vv + ((size_t)b * SS + t) * DD + half * 64);
        float4* drow = reinterpret_cast<float4*>(Ks + k * PK + half * 64);
        #pragma unroll
        for (int c4 = 0; c4 < 16; ++c4) drow[c4] = srow[c4];
    }
    __syncthreads();

    // PV: thread (ty,tx): queries ty+16a, dims tx*8..tx*8+7
    float outv[4][8];
    #pragma unroll
    for (int a = 0; a < 4; ++a)
        #pragma unroll
        for (int e = 0; e < 8; ++e) outv[a][e] = 0.f;

    for (int k = 0; k < 128; k += 4) {
        float4 pv[4];
        #pragma unroll
        for (int a = 0; a < 4; ++a)
            pv[a] = *reinterpret_cast<const float4*>(&Qs[(ty + 16 * a) * PK + k]);
        #pragma unroll
        for (int kk = 0; kk < 4; ++kk) {
            const float4 v0 = *reinterpret_cast<const float4*>(&Ks[(k + kk) * PK + tx * 8]);
            const float4 v1 = *reinterpret_cast<const float4*>(&Ks[(k + kk) * PK + tx * 8 + 4]);
            #pragma unroll
            for (int a = 0; a < 4; ++a) {
                const float p = (kk == 0) ? pv[a].x : (kk == 1) ? pv[a].y
                              : (kk == 2) ? pv[a].z : pv[a].w;
                outv[a][0] = fmaf(p, v0.x, outv[a][0]);
                outv[a][1] = fmaf(p, v0.y, outv[a][1]);
                outv[a][2] = fmaf(p, v0.z, outv[a][2]);
                outv[a][3] = fmaf(p, v0.w, outv[a][3]);
                outv[a][4] = fmaf(p, v1.x, outv[a][4]);
                outv[a][5] = fmaf(p, v1.y, outv[a][5]);
                outv[a][6] = fmaf(p, v1.z, outv[a][6]);
                outv[a][7] = fmaf(p, v1.w, outv[a][7]);
            }
        }
    }

    // scatter per-round outputs
    #pragma unroll
    for (int a = 0; a < 4; ++a) {
        const int q = ty + 16 * a;
        const int t = tks[q];
        const size_t base = (((size_t)b * HH + h) * SS + t) * DD + tx * 8;
        if (!obf16) {
            float* op = (float*)o_ws;
            *reinterpret_cast<float4*>(op + base)     = make_float4(outv[a][0], outv[a][1], outv[a][2], outv[a][3]);
            *reinterpret_cast<float4*>(op + base + 4) = make_float4(outv[a][4], outv[a][5], outv[a][6], outv[a][7]);
        } else {
            unsigned short* op = (unsigned short*)o_ws;
            uint4 pkd;
            pkd.x = (unsigned int)f2bf_rne(outv[a][0]) | ((unsigned int)f2bf_rne(outv[a][1]) << 16);
            pkd.y = (unsigned int)f2bf_rne(outv[a][2]) | ((unsigned int)f2bf_rne(outv[a][3]) << 16);
            pkd.z = (unsigned int)f2bf_rne(outv[a][4]) | ((unsigned int)f2bf_rne(outv[a][5]) << 16);
            pkd.w = (unsigned int)f2bf_rne(outv[a][6]) | ((unsigned int)f2bf_rne(outv[a][7]) << 16);
            *reinterpret_cast<uint4*>(op + base) = pkd;
        }
    }
}

// ---------------- Kernel D: softmax-combine over hash rounds -----------------
__global__ __launch_bounds__(256) void combine_kernel(
    const float* __restrict__ logits_ws, const void* __restrict__ o_ws,
    float* __restrict__ outp, const int obf16)
{
    const int gid = blockIdx.x * 256 + threadIdx.x;
    const int row = gid >> 5;     // (b,t)
    const int seg = gid & 31;     // 4-float segment of D
    const int b = row >> 12;
    const int t = row & 4095;

    float l[8];
    float m = -3.0e38f;
    #pragma unroll
    for (int hh = 0; hh < 8; ++hh) {
        l[hh] = logits_ws[((size_t)b * HH + hh) * SS + t];
        m = fmaxf(m, l[hh]);
    }
    float ssum = 0.f;
    #pragma unroll
    for (int hh = 0; hh < 8; ++hh) { l[hh] = expf(l[hh] - m); ssum += l[hh]; }
    const float inv = 1.0f / ssum;

    float a0 = 0.f, a1 = 0.f, a2 = 0.f, a3 = 0.f;
    #pragma unroll
    for (int hh = 0; hh < 8; ++hh) {
        const float wgt = l[hh] * inv;
        const size_t base = (((size_t)b * HH + hh) * SS + t) * DD + seg * 4;
        if (!obf16) {
            float4 ov = *reinterpret_cast<const float4*>((const float*)o_ws + base);
            a0 = fmaf(wgt, ov.x, a0); a1 = fmaf(wgt, ov.y, a1);
            a2 = fmaf(wgt, ov.z, a2); a3 = fmaf(wgt, ov.w, a3);
        } else {
            uint2 u = *reinterpret_cast<const uint2*>((const unsigned short*)o_ws + base);
            a0 = fmaf(wgt, bf2f((unsigned short)(u.x & 0xffffu)), a0);
            a1 = fmaf(wgt, bf2f((unsigned short)(u.x >> 16)), a1);
            a2 = fmaf(wgt, bf2f((unsigned short)(u.y & 0xffffu)), a2);
            a3 = fmaf(wgt, bf2f((unsigned short)(u.y >> 16)), a3);
        }
    }
    *reinterpret_cast<float4*>(outp + ((size_t)b * SS + t) * DD + seg * 4) =
        make_float4(a0, a1, a2, a3);
}

extern "C" void kernel_launch(void* const* d_in, const int* in_sizes, int n_in,
                              void* d_out, int out_size, void* d_ws, size_t ws_size,
                              hipStream_t stream) {
    const float* qk  = (const float*)d_in[0];
    const float* v   = (const float*)d_in[1];
    const float* rot = (const float*)d_in[2];

    float* out        = (float*)d_out;
    float* bucket_out = out + (size_t)BB * SS * DD;   // buckets written as f32

    char* ws = (char*)d_ws;
    int*            st        = (int*)ws;                              // 1,048,576 B
    unsigned char*  bucket_ws = (unsigned char*)(ws + 1048576);        //   262,144 B
    float*          logits_ws = (float*)(ws + 1048576 + 262144);       // 1,048,576 B
    void*           o_ws      = (void*)(ws + 2359296);                 // big scratch

    const size_t need_f32 = 2359296ull + (size_t)BB * HH * SS * DD * 4ull; // 136.6 MB
    const int obf16 = (ws_size >= need_f32) ? 0 : 1;

    hipLaunchKernelGGL(hash_kernel,    dim3(1024), dim3(256), 0, stream, qk, rot, bucket_ws, bucket_out);
    hipLaunchKernelGGL(sort_kernel,    dim3(64),   dim3(256), 0, stream, bucket_ws, st);
    hipLaunchKernelGGL(attn_kernel,    dim3(4096), dim3(256), 0, stream, qk, v, st, logits_ws, o_ws, obf16);
    hipLaunchKernelGGL(combine_kernel, dim3(4096), dim3(256), 0, stream, logits_ws, o_ws, out, obf16);
}

// Round 4
// 249.931 us; speedup vs baseline: 2.1806x; 2.1806x over previous
//
#include <hip/hip_runtime.h>
#include <hip/hip_bf16.h>

#define BB 8
#define SS 4096
#define DD 128
#define HH 8
#define NBUCK 64
#define CHUNKSZ 64
#define NCHUNK 512      // HH*SS/CHUNKSZ
#define HSTOT 32768     // HH*SS
#define PK 132          // padded LDS row stride (floats) -- hash kernel only
#define ROWB 272        // bf16 tile row stride in bytes (128*2 + 16 pad)

typedef __attribute__((ext_vector_type(8))) short short8_t;   // 8 bf16 = 4 VGPR
typedef __attribute__((ext_vector_type(4))) float f32x4;

static __device__ __forceinline__ unsigned short f2bf_rne(float f) {
    unsigned int x = __float_as_uint(f);
    unsigned int r = (x + 0x7fffu + ((x >> 16) & 1u)) >> 16;
    return (unsigned short)r;
}
static __device__ __forceinline__ unsigned int pk2bf(float lo, float hi) {
    return (unsigned int)f2bf_rne(lo) | ((unsigned int)f2bf_rne(hi) << 16);
}
static __device__ __forceinline__ float bf2f(unsigned short u) {
    return __uint_as_float(((unsigned int)u) << 16);
}

// ---------------- Kernel A: LSH hashing (f64 accumulate for argmax safety) ----
__global__ __launch_bounds__(256) void hash_kernel(
    const float* __restrict__ qk, const float* __restrict__ rot,
    unsigned char* __restrict__ bucket_ws, float* __restrict__ bucket_out)
{
    __shared__ float qtile[32 * PK];
    const int tid = threadIdx.x;
    const int blk = blockIdx.x;            // 0..1023 = b*128 + tblk
    const int b  = blk >> 7;
    const int t0 = (blk & 127) * 32;

    const float* src = qk + ((size_t)b * SS + t0) * DD;
    #pragma unroll
    for (int c = 0; c < 4; ++c) {
        int idx = c * 1024 + tid * 4;
        float4 val = *reinterpret_cast<const float4*>(src + idx);
        int row = idx >> 7, col = idx & 127;
        *reinterpret_cast<float4*>(&qtile[row * PK + col]) = val;
    }
    __syncthreads();

    const int i = tid & 31;   // token within tile
    const int h = tid >> 5;   // hash round
    double acc[32];
    #pragma unroll
    for (int j = 0; j < 32; ++j) acc[j] = 0.0;

    const float* rbase = rot + h * 32;     // rotations[f][h][j]: f stride 256
    for (int f = 0; f < DD; ++f) {
        double qd = (double)qtile[i * PK + f];
        const float4* r4 = reinterpret_cast<const float4*>(rbase + (size_t)f * (HH * 32));
        #pragma unroll
        for (int j4 = 0; j4 < 8; ++j4) {
            float4 rv = r4[j4];
            acc[j4*4+0] = fma(qd, (double)rv.x, acc[j4*4+0]);
            acc[j4*4+1] = fma(qd, (double)rv.y, acc[j4*4+1]);
            acc[j4*4+2] = fma(qd, (double)rv.z, acc[j4*4+2]);
            acc[j4*4+3] = fma(qd, (double)rv.w, acc[j4*4+3]);
        }
    }

    // argmax over [rot, -rot], first-occurrence tie semantics
    float bv = -3.0e38f; int bi = 0;
    #pragma unroll
    for (int j = 0; j < 32; ++j) { float r = (float)acc[j];  if (r > bv) { bv = r; bi = j; } }
    #pragma unroll
    for (int j = 0; j < 32; ++j) { float r = -(float)acc[j]; if (r > bv) { bv = r; bi = 32 + j; } }

    size_t o = ((size_t)b * HH + h) * SS + (t0 + i);
    bucket_ws[o]  = (unsigned char)bi;
    bucket_out[o] = (float)(bi + h * NBUCK);
}

// ---------------- Kernel B: stable counting sort per (b,h) -------------------
__global__ __launch_bounds__(256) void sort_kernel(
    const unsigned char* __restrict__ bucket_ws, int* __restrict__ st)
{
    __shared__ unsigned int hist[256 * 65];   // padded stride 65
    __shared__ unsigned int totals[64];
    const int tid = threadIdx.x;
    const int bh  = blockIdx.x;               // 0..63 = b*8+h

    unsigned int* hrow = &hist[tid * 65];
    #pragma unroll
    for (int j = 0; j < 65; ++j) hrow[j] = 0u;

    const uint4 raw = *reinterpret_cast<const uint4*>(bucket_ws + (size_t)bh * SS + tid * 16);
    unsigned int w[4] = {raw.x, raw.y, raw.z, raw.w};

    #pragma unroll
    for (int c = 0; c < 16; ++c) {
        unsigned int bk = (w[c >> 2] >> ((c & 3) * 8)) & 255u;
        hrow[bk] += 1u;
    }
    __syncthreads();

    if (tid < 64) {                            // per-bucket exclusive scan over chunks
        unsigned int run = 0;
        for (int c2 = 0; c2 < 256; ++c2) {
            unsigned int x = hist[c2 * 65 + tid];
            hist[c2 * 65 + tid] = run;
            run += x;
        }
        totals[tid] = run;
    }
    __syncthreads();
    if (tid == 0) {                            // exclusive scan over buckets
        unsigned int base = 0;
        for (int k = 0; k < 64; ++k) { unsigned int x = totals[k]; totals[k] = base; base += x; }
    }
    __syncthreads();

    int* dst = st + (size_t)bh * SS;
    #pragma unroll
    for (int c = 0; c < 16; ++c) {
        unsigned int bk = (w[c >> 2] >> ((c & 3) * 8)) & 255u;
        unsigned int pos = totals[bk] + hrow[bk];
        hrow[bk] += 1u;
        dst[pos] = tid * 16 + c;               // token id, stable by t
    }
}

// ---------------- Kernel C: chunked attention via bf16 MFMA ------------------
// LDS map (bytes):
//   [0,      34816)  Kb: 128 rows x 128 bf16, row stride 272 (later reused as Vt2)
//   [34816,  52224)  P : 64 rows x 128 bf16, row stride 272  (first reused as psums[256] f32)
//   [52224,  52736)  tks[128] int
//   [52736,  53248)  ninv[128] f32
__global__ __launch_bounds__(256, 3) void attn_kernel(
    const float* __restrict__ qk, const float* __restrict__ vv,
    const int* __restrict__ st, float* __restrict__ logits_ws,
    void* __restrict__ o_ws, const int obf16)
{
    __shared__ __align__(16) char smem[53248];
    char*  Kb    = smem;
    char*  Pb    = smem + 34816;
    int*   tks   = (int*)(smem + 52224);
    float* ninv  = (float*)(smem + 52736);
    float* psums = (float*)(smem + 34816);     // transient, before P is written

    const int tid = threadIdx.x;
    const int bc  = blockIdx.x;
    const int b   = bc >> 9;
    const int c   = bc & 511;                  // global chunk 0..511
    const int h   = c >> 6;

    if (tid < 128) {
        int src_c = (tid < 64) ? c : ((c == 0) ? (NCHUNK - 1) : (c - 1));
        tks[tid] = st[(size_t)b * HSTOT + (size_t)src_c * CHUNKSZ + (tid & 63)];
    }
    __syncthreads();

    // ---- stage K (raw qk rows, bf16) + sum-of-squares -----------------------
    {
        const int row = tid >> 1, half = tid & 1;
        const int t = tks[row];
        const float* srow = qk + ((size_t)b * SS + t) * DD + half * 64;
        char* krow = Kb + (size_t)row * ROWB + half * 128;
        float ss = 0.f;
        #pragma unroll
        for (int i = 0; i < 8; ++i) {
            float4 v0 = *reinterpret_cast<const float4*>(srow + i * 8);
            float4 v1 = *reinterpret_cast<const float4*>(srow + i * 8 + 4);
            ss = fmaf(v0.x, v0.x, ss); ss = fmaf(v0.y, v0.y, ss);
            ss = fmaf(v0.z, v0.z, ss); ss = fmaf(v0.w, v0.w, ss);
            ss = fmaf(v1.x, v1.x, ss); ss = fmaf(v1.y, v1.y, ss);
            ss = fmaf(v1.z, v1.z, ss); ss = fmaf(v1.w, v1.w, ss);
            uint4 pk;
            pk.x = pk2bf(v0.x, v0.y); pk.y = pk2bf(v0.z, v0.w);
            pk.z = pk2bf(v1.x, v1.y); pk.w = pk2bf(v1.z, v1.w);
            *reinterpret_cast<uint4*>(krow + i * 16) = pk;
        }
        psums[tid] = ss;
    }
    __syncthreads();
    if (tid < 128) ninv[tid] = rsqrtf(psums[2 * tid] + psums[2 * tid + 1] + 1e-6f);
    __syncthreads();

    const int w  = tid >> 6;     // wave id: q-tile rows 16w..16w+15
    const int ln = tid & 63;
    const int cc = ln & 15;      // fragment col lane
    const int g  = ln >> 4;      // fragment k-group / row-group

    // ---- QK^T: 4 A-frags (Q = Kb rows 16w+cc), 8 k-tiles --------------------
    short8_t aq[4];
    #pragma unroll
    for (int ks = 0; ks < 4; ++ks)
        aq[ks] = *reinterpret_cast<const short8_t*>(Kb + (size_t)(16 * w + cc) * ROWB + ks * 64 + g * 16);

    f32x4 acc[8];
    #pragma unroll
    for (int j = 0; j < 8; ++j) {
        acc[j] = (f32x4){0.f, 0.f, 0.f, 0.f};
        #pragma unroll
        for (int ks = 0; ks < 4; ++ks) {
            short8_t bk = *reinterpret_cast<const short8_t*>(Kb + (size_t)(16 * j + cc) * ROWB + ks * 64 + g * 16);
            acc[j] = __builtin_amdgcn_mfma_f32_16x16x32_bf16(aq[ks], bk, acc[j], 0, 0, 0);
        }
    }

    // ---- softmax over 128 keys per q-row (rows q = 16w + 4g + jr) -----------
    const float SCALE = 0.088388347648318447f;   // 128^-0.5
    const int   tkk   = tks[16 * 0 + cc];        // placeholder to keep reads simple below
    (void)tkk;
    float lse[4];
    float pr[8][4];
    #pragma unroll
    for (int jr = 0; jr < 4; ++jr) {
        const int q  = 16 * w + 4 * g + jr;
        const int tq = tks[q];
        float m = -3.0e38f;
        #pragma unroll
        for (int j = 0; j < 8; ++j) {
            const int k = 16 * j + cc;
            float val = acc[j][jr] * (ninv[k] * SCALE);
            if (tks[k] == tq) val = -1e5f;
            pr[j][jr] = val;
            m = fmaxf(m, val);
        }
        #pragma unroll
        for (int off = 1; off < 16; off <<= 1) m = fmaxf(m, __shfl_xor(m, off));
        float ssum = 0.f;
        #pragma unroll
        for (int j = 0; j < 8; ++j) { float ex = expf(pr[j][jr] - m); pr[j][jr] = ex; ssum += ex; }
        #pragma unroll
        for (int off = 1; off < 16; off <<= 1) ssum += __shfl_xor(ssum, off);
        const float inv = 1.0f / ssum;
        #pragma unroll
        for (int j = 0; j < 8; ++j) pr[j][jr] *= inv;
        lse[jr] = m + logf(ssum);
    }

    __syncthreads();   // all waves done reading Kb; safe to overwrite with Vt2

    // ---- write P (bf16) ------------------------------------------------------
    #pragma unroll
    for (int jr = 0; jr < 4; ++jr) {
        const int q = 16 * w + 4 * g + jr;
        #pragma unroll
        for (int j = 0; j < 8; ++j)
            *reinterpret_cast<unsigned short*>(Pb + (size_t)q * ROWB + (16 * j + cc) * 2) = f2bf_rne(pr[j][jr]);
    }
    // ---- lse scatter ---------------------------------------------------------
    if (cc == 0) {
        #pragma unroll
        for (int jr = 0; jr < 4; ++jr) {
            const int q = 16 * w + 4 * g + jr;
            logits_ws[((size_t)b * HH + h) * SS + tks[q]] = lse[jr];
        }
    }

    // ---- stage V transposed: Vt2[d][kpair] = pack(V[2kp][d], V[2kp+1][d]) ----
    {
        const int kp = tid & 63;
        const int db = tid >> 6;           // dim block: dims db*32..db*32+31
        const int ta = tks[2 * kp], tb = tks[2 * kp + 1];
        const float* ra = vv + ((size_t)b * SS + ta) * DD + db * 32;
        const float* rb = vv + ((size_t)b * SS + tb) * DD + db * 32;
        #pragma unroll
        for (int i = 0; i < 32; i += 4) {
            float4 va = *reinterpret_cast<const float4*>(ra + i);
            float4 vb = *reinterpret_cast<const float4*>(rb + i);
            const int d0 = db * 32 + i;
            *reinterpret_cast<unsigned int*>(Kb + (size_t)(d0 + 0) * ROWB + kp * 4) = pk2bf(va.x, vb.x);
            *reinterpret_cast<unsigned int*>(Kb + (size_t)(d0 + 1) * ROWB + kp * 4) = pk2bf(va.y, vb.y);
            *reinterpret_cast<unsigned int*>(Kb + (size_t)(d0 + 2) * ROWB + kp * 4) = pk2bf(va.z, vb.z);
            *reinterpret_cast<unsigned int*>(Kb + (size_t)(d0 + 3) * ROWB + kp * 4) = pk2bf(va.w, vb.w);
        }
    }
    __syncthreads();

    // ---- PV: A = P rows (16w+cc), B = Vt2 columns ----------------------------
    short8_t pa[4];
    #pragma unroll
    for (int ks = 0; ks < 4; ++ks)
        pa[ks] = *reinterpret_cast<const short8_t*>(Pb + (size_t)(16 * w + cc) * ROWB + ks * 64 + g * 16);

    f32x4 oacc[8];
    #pragma unroll
    for (int dt = 0; dt < 8; ++dt) {
        oacc[dt] = (f32x4){0.f, 0.f, 0.f, 0.f};
        #pragma unroll
        for (int ks = 0; ks < 4; ++ks) {
            short8_t vb = *reinterpret_cast<const short8_t*>(Kb + (size_t)(16 * dt + cc) * ROWB + ks * 64 + g * 16);
            oacc[dt] = __builtin_amdgcn_mfma_f32_16x16x32_bf16(pa[ks], vb, oacc[dt], 0, 0, 0);
        }
    }

    // ---- scatter per-round outputs: rows q = 16w + 4g + jr, dims 16dt + cc ---
    #pragma unroll
    for (int jr = 0; jr < 4; ++jr) {
        const int q = 16 * w + 4 * g + jr;
        const int t = tks[q];
        const size_t base = (((size_t)b * HH + h) * SS + t) * DD + cc;
        if (!obf16) {
            float* op = (float*)o_ws;
            #pragma unroll
            for (int dt = 0; dt < 8; ++dt) op[base + 16 * dt] = oacc[dt][jr];
        } else {
            unsigned short* op = (unsigned short*)o_ws;
            #pragma unroll
            for (int dt = 0; dt < 8; ++dt) op[base + 16 * dt] = f2bf_rne(oacc[dt][jr]);
        }
    }
}

// ---------------- Kernel D: softmax-combine over hash rounds -----------------
__global__ __launch_bounds__(256) void combine_kernel(
    const float* __restrict__ logits_ws, const void* __restrict__ o_ws,
    float* __restrict__ outp, const int obf16)
{
    const int gid = blockIdx.x * 256 + threadIdx.x;
    const int row = gid >> 5;     // (b,t)
    const int seg = gid & 31;     // 4-float segment of D
    const int b = row >> 12;
    const int t = row & 4095;

    float l[8];
    float m = -3.0e38f;
    #pragma unroll
    for (int hh = 0; hh < 8; ++hh) {
        l[hh] = logits_ws[((size_t)b * HH + hh) * SS + t];
        m = fmaxf(m, l[hh]);
    }
    float ssum = 0.f;
    #pragma unroll
    for (int hh = 0; hh < 8; ++hh) { l[hh] = expf(l[hh] - m); ssum += l[hh]; }
    const float inv = 1.0f / ssum;

    float a0 = 0.f, a1 = 0.f, a2 = 0.f, a3 = 0.f;
    #pragma unroll
    for (int hh = 0; hh < 8; ++hh) {
        const float wgt = l[hh] * inv;
        const size_t base = (((size_t)b * HH + hh) * SS + t) * DD + seg * 4;
        if (!obf16) {
            float4 ov = *reinterpret_cast<const float4*>((const float*)o_ws + base);
            a0 = fmaf(wgt, ov.x, a0); a1 = fmaf(wgt, ov.y, a1);
            a2 = fmaf(wgt, ov.z, a2); a3 = fmaf(wgt, ov.w, a3);
        } else {
            uint2 u = *reinterpret_cast<const uint2*>((const unsigned short*)o_ws + base);
            a0 = fmaf(wgt, bf2f((unsigned short)(u.x & 0xffffu)), a0);
            a1 = fmaf(wgt, bf2f((unsigned short)(u.x >> 16)), a1);
            a2 = fmaf(wgt, bf2f((unsigned short)(u.y & 0xffffu)), a2);
            a3 = fmaf(wgt, bf2f((unsigned short)(u.y >> 16)), a3);
        }
    }
    *reinterpret_cast<float4*>(outp + ((size_t)b * SS + t) * DD + seg * 4) =
        make_float4(a0, a1, a2, a3);
}

extern "C" void kernel_launch(void* const* d_in, const int* in_sizes, int n_in,
                              void* d_out, int out_size, void* d_ws, size_t ws_size,
                              hipStream_t stream) {
    const float* qk  = (const float*)d_in[0];
    const float* v   = (const float*)d_in[1];
    const float* rot = (const float*)d_in[2];

    float* out        = (float*)d_out;
    float* bucket_out = out + (size_t)BB * SS * DD;   // buckets written as f32

    char* ws = (char*)d_ws;
    int*            st        = (int*)ws;                              // 1,048,576 B
    unsigned char*  bucket_ws = (unsigned char*)(ws + 1048576);        //   262,144 B
    float*          logits_ws = (float*)(ws + 1048576 + 262144);       // 1,048,576 B
    void*           o_ws      = (void*)(ws + 2359296);                 // big scratch

    const size_t need_f32 = 2359296ull + (size_t)BB * HH * SS * DD * 4ull; // 136.6 MB
    const int obf16 = (ws_size >= need_f32) ? 0 : 1;

    hipLaunchKernelGGL(hash_kernel,    dim3(1024), dim3(256), 0, stream, qk, rot, bucket_ws, bucket_out);
    hipLaunchKernelGGL(sort_kernel,    dim3(64),   dim3(256), 0, stream, bucket_ws, st);
    hipLaunchKernelGGL(attn_kernel,    dim3(4096), dim3(256), 0, stream, qk, v, st, logits_ws, o_ws, obf16);
    hipLaunchKernelGGL(combine_kernel, dim3(4096), dim3(256), 0, stream, logits_ws, o_ws, out, obf16);
}